// Round 2
// baseline (230.285 us; speedup 1.0000x reference)
//
#include <hip/hip_runtime.h>
#include <math.h>

namespace {

constexpr int kRays    = 65536;
constexpr int kSamples = 128;
constexpr float kEpsilonBig = 1.0e10f;   // EPSILON in the reference

// d_out layout: outputs concatenated flat in reference return order
constexpr int OFF_RGB   = 0;                          // (kRays, 3)
constexpr int OFF_DEPTH = OFF_RGB + kRays * 3;        // (kRays,)
constexpr int OFF_W     = OFF_DEPTH + kRays;          // (kRays, 128)
constexpr int OFF_M     = OFF_W + kRays * kSamples;   // (kRays, 128)
constexpr int OFF_ACC   = OFF_M + kRays * kSamples;   // (kRays,)
constexpr int OFF_DISP  = OFF_ACC + kRays;            // (kRays,)

__global__ __launch_bounds__(256) void volume_render_kernel(
    const float* __restrict__ rf,     // (kRays, 128, 4)
    const float* __restrict__ depth,  // (kRays, 128)
    const float* __restrict__ rd,     // (kRays, 3)
    float* __restrict__ out)
{
  const int lane = threadIdx.x & 63;
  const int ray  = (blockIdx.x * blockDim.x + threadIdx.x) >> 6;  // wave id
  // grid exactly covers kRays waves; no bounds check needed

  // ---- coalesced loads: lane owns samples s0=lane and s1=lane+64 ----
  const float4* rf4 = reinterpret_cast<const float4*>(rf);
  const float4 v0 = rf4[ray * kSamples + lane];
  const float4 v1 = rf4[ray * kSamples + lane + 64];
  const float  d0 = depth[ray * kSamples + lane];
  const float  d1 = depth[ray * kSamples + lane + 64];

  const float rx = rd[ray * 3 + 0];
  const float ry = rd[ray * 3 + 1];
  const float rz = rd[ray * 3 + 2];
  const double nrm = sqrt((double)rx * rx + (double)ry * ry + (double)rz * rz);

  // ---- deltas (need depth[s+1]) ----
  float nd0 = __shfl_down(d0, 1);          // depth[lane+1] for lane<63
  const float d_at_64 = __shfl(d1, 0);     // depth[64]
  if (lane == 63) nd0 = d_at_64;
  const float nd1 = __shfl_down(d1, 1);    // depth[lane+65]

  const double delta0 = ((double)nd0 - (double)d0) * nrm;
  const double delta1 = (lane == 63) ? (double)kEpsilonBig * nrm
                                     : ((double)nd1 - (double)d1) * nrm;

  // ---- alpha, transmittance factor t = 1 - alpha + 1e-10 ----
  const double sig0 = (v0.w > 0.0f) ? (double)v0.w : 0.0;
  const double sig1 = (v1.w > 0.0f) ? (double)v1.w : 0.0;
  const double alpha0 = 1.0 - exp(-sig0 * delta0);
  const double alpha1 = 1.0 - exp(-sig1 * delta1);
  double t0 = 1.0 - alpha0 + 1e-10;
  double t1 = 1.0 - alpha1 + 1e-10;

  // ---- exclusive cumprod over 128 samples (two 64-wide wave scans) ----
  double p0 = t0, p1 = t1;
#pragma unroll
  for (int off = 1; off < 64; off <<= 1) {
    const double u0 = __shfl_up(p0, off);
    const double u1 = __shfl_up(p1, off);
    if (lane >= off) { p0 *= u0; p1 *= u1; }
  }
  const double tot0 = __shfl(p0, 63);      // prod t[0..63]
  double e0 = __shfl_up(p0, 1);            // inclusive -> exclusive
  double e1 = __shfl_up(p1, 1);
  if (lane == 0) { e0 = 1.0; e1 = 1.0; }
  const double T0 = e0;                    // T_i at s = lane
  const double T1 = tot0 * e1;             // T_i at s = lane + 64

  const double w0 = alpha0 * T0;
  const double w1 = alpha1 * T1;

  // ---- full-size outputs (coalesced) ----
  const int base = ray * kSamples + lane;
  out[OFF_W + base]      = (float)w0;
  out[OFF_W + base + 64] = (float)w1;
  out[OFF_M + base]      = (T0 > 0.001) ? 1.0f : 0.0f;
  out[OFF_M + base + 64] = (T1 > 0.001) ? 1.0f : 0.0f;

  // ---- wave reductions: rgb (3), acc, depth ----
  double r   = w0 * (double)v0.x + w1 * (double)v1.x;
  double g   = w0 * (double)v0.y + w1 * (double)v1.y;
  double b   = w0 * (double)v0.z + w1 * (double)v1.z;
  double acc = w0 + w1;
  double dm  = w0 * (double)d0 + w1 * (double)d1;
#pragma unroll
  for (int off = 32; off > 0; off >>= 1) {
    r   += __shfl_xor(r, off);
    g   += __shfl_xor(g, off);
    b   += __shfl_xor(b, off);
    acc += __shfl_xor(acc, off);
    dm  += __shfl_xor(dm, off);
  }

  if (lane == 0) {
    out[OFF_RGB + ray * 3 + 0] = (float)r;
    out[OFF_RGB + ray * 3 + 1] = (float)g;
    out[OFF_RGB + ray * 3 + 2] = (float)b;
    out[OFF_DEPTH + ray] = (float)dm;
    out[OFF_ACC + ray]   = (float)acc;
    const double q = dm / acc;            // may be NaN (0/0)
    double disp;
    if (isnan(q)) {
      disp = 0.0;                         // jnp.maximum propagates NaN -> where() zeroes it
    } else {
      disp = 1.0 / fmax(1e-10, q);        // q==inf -> disp 0, matches reference
    }
    out[OFF_DISP + ray] = (float)disp;
  }
}

}  // namespace

extern "C" void kernel_launch(void* const* d_in, const int* in_sizes, int n_in,
                              void* d_out, int out_size, void* d_ws, size_t ws_size,
                              hipStream_t stream) {
  const float* rf    = (const float*)d_in[0];   // radiance_field (65536,128,4)
  const float* depth = (const float*)d_in[1];   // depth_values   (65536,128)
  const float* rd    = (const float*)d_in[2];   // ray_directions (65536,3)
  float* out = (float*)d_out;

  // one wave per ray: 65536 waves = 16384 blocks of 256 threads (4 waves)
  const int blocks = kRays / 4;
  volume_render_kernel<<<blocks, 256, 0, stream>>>(rf, depth, rd, out);
}